// Round 10
// baseline (127.909 us; speedup 1.0000x reference)
//
#include <hip/hip_runtime.h>

#define NF 40
#define ED 128
#define NB 1024
#define NIX 780
#define XROW (NF * ED)      // 5120
#define KROW (NIX * ED)     // 99840
#define XB_BYTES (NB * NF * ED * 2)   // 13,107,200
#define KB_BYTES (NIX * ED * ED * 2)  // 25,559,040
#define WS_NEED (XB_BYTES + KB_BYTES)

typedef __attribute__((ext_vector_type(8))) short bf16x8;
typedef __attribute__((ext_vector_type(4))) float f32x4;
typedef __attribute__((ext_vector_type(4))) unsigned short ushx4;
typedef __attribute__((ext_vector_type(8))) unsigned short ushx8;

__device__ __forceinline__ unsigned short f2bf(float x) {
  unsigned int u = __float_as_uint(x);
  u = (u + 0x7FFFu + ((u >> 16) & 1u)) >> 16;
  return (unsigned short)u;
}
__device__ __forceinline__ float bf2f(unsigned short h) {
  return __uint_as_float(((unsigned int)h) << 16);
}

#define GLOAD16(gsrc, ldst)                                                    \
  __builtin_amdgcn_global_load_lds(                                            \
      (const __attribute__((address_space(1))) void*)(gsrc),                   \
      (__attribute__((address_space(3))) void*)(ldst), 16, 0, 0)

// ---- fused prepass: x fp32->bf16 (blocks 0..2559), K [e][n][d]->[n][e][d] bf16 ----
__global__ void cvt_fused(const float* __restrict__ x, const float* __restrict__ kr,
                          unsigned short* __restrict__ xb, unsigned short* __restrict__ kb) {
  const int blk = blockIdx.x;
  if (blk < 2560) {
    const size_t g = ((size_t)blk * 256 + threadIdx.x) * 8;
    float4 a = *reinterpret_cast<const float4*>(x + g);
    float4 b = *reinterpret_cast<const float4*>(x + g + 4);
    ushx8 h;
    h[0] = f2bf(a.x); h[1] = f2bf(a.y); h[2] = f2bf(a.z); h[3] = f2bf(a.w);
    h[4] = f2bf(b.x); h[5] = f2bf(b.y); h[6] = f2bf(b.z); h[7] = f2bf(b.w);
    *reinterpret_cast<ushx8*>(xb + g) = h;
  } else {
    const size_t g = ((size_t)(blk - 2560) * 256 + threadIdx.x) * 4;
    const int d = (int)(g & 127);
    const size_t t = g >> 7;
    const int e = (int)(t & 127);
    const int n = (int)(t >> 7);
    float4 v = *reinterpret_cast<const float4*>(kr + ((size_t)e * NIX + n) * ED + d);
    ushx4 h;
    h[0] = f2bf(v.x); h[1] = f2bf(v.y); h[2] = f2bf(v.z); h[3] = f2bf(v.w);
    *reinterpret_cast<ushx4*>(kb + g) = h;
  }
}

// ---- main kernel: e-split warps, 32-row b-tiles, DOUBLE-BUFFERED staging,
// ---- 1 barrier/tile, deferred dot epilogue (m97-shaped iteration).
__launch_bounds__(256, 4)
__global__ void opn_ws(const unsigned short* __restrict__ xb,
                       const unsigned short* __restrict__ kb,
                       float* __restrict__ out) {
  // 32 KB: K prologue staging; then bufA (16 KB) | bufB (16 KB).
  __shared__ unsigned short S[16384];
  __shared__ float scratchF[1024];   // [warp][tile][b] partials, 4 KB

  const int bid = blockIdx.x;
  const int g8 = bid & 7;
  const int n = ((bid >> 3) << 1) + (g8 & 1);   // pair index, 0..779
  const int b0base = (g8 >> 1) * 256;           // b-slice (XCD-locked)

  const int tid = threadIdx.x;
  const int lane = tid & 63;
  const int w = tid >> 6;
  const int lm = lane & 15;
  const int lq = lane >> 4;
  const int col8 = lm * 8;

  // pair (fi, fj)
  int fi = 0, base = 0;
  while (base + (NF - 1 - fi) <= n) { base += NF - 1 - fi; ++fi; }
  const int fj = fi + 1 + (n - base);

  // ---- stage K (32 KB over both buffers) ----
  {
    const unsigned short* ks = kb + (size_t)n * (ED * ED);
    #pragma unroll
    for (int j = 0; j < 8; ++j) {
      const int chunk = j * 4 + w;           // 0..31, 1KB each
      const int r = chunk * 4 + lq;          // 0..127
      const int c = col8 ^ ((r & 7) << 3);
      GLOAD16(ks + r * ED + c, S + chunk * 512);
    }
  }
  __syncthreads();

  // ---- hoist this warp's e-quarter: A[m=e][k=d], e = w*32 + f*16 + lm ----
  bf16x8 afr[4][2];
  #pragma unroll
  for (int kk = 0; kk < 4; ++kk)
    #pragma unroll
    for (int f = 0; f < 2; ++f) {
      const int r = w * 32 + f * 16 + lm;
      afr[kk][f] = *reinterpret_cast<const bf16x8*>(
          &S[r * ED + ((kk * 32 + lq * 8) ^ ((r & 7) << 3))]);
    }
  #pragma unroll
  for (int kk = 0; kk < 4; ++kk)
    #pragma unroll
    for (int f = 0; f < 2; ++f)
      asm volatile("" : "+v"(afr[kk][f]));   // pin: forbid remat from LDS
  __syncthreads();                            // all warps done reading K area

  unsigned short* bufA = S;                   // P [0..4095], Q [4096..8191]
  unsigned short* bufB = S + 8192;

  auto stage = [&](unsigned short* buf, int t) {
    const int b0 = b0base + t * 32;
    #pragma unroll
    for (int j = 0; j < 2; ++j) {
      const int chunk = j * 4 + w;           // 0..7
      const int r = chunk * 4 + lq;          // 0..31
      const int c = col8 ^ ((r & 7) << 3);
      const size_t xoff = (size_t)(b0 + r) * XROW + c;
      GLOAD16(xb + xoff + (size_t)fi * ED, buf + chunk * 512);
      GLOAD16(xb + xoff + (size_t)fj * ED, buf + 4096 + chunk * 512);
    }
  };

  float res[8][2];   // pre-shuffle dot partials, statically indexed

  stage(bufA, 0);
  __syncthreads();   // tile 0 staged (vmcnt drained by barrier)

  #pragma unroll
  for (int t = 0; t < 8; ++t) {
    unsigned short* cur = (t & 1) ? bufB : bufA;
    unsigned short* nxt = (t & 1) ? bufA : bufB;
    if (t + 1 < 8) stage(nxt, t + 1);        // flies under compute(t)

    const unsigned short* Pl = cur;
    const unsigned short* Ql = cur + 4096;

    // ---- T-quarter = K_w @ P^T : D[m=e][col=b], nt = b-subtile ----
    f32x4 acc[2][2];
    #pragma unroll
    for (int f = 0; f < 2; ++f)
      #pragma unroll
      for (int nt = 0; nt < 2; ++nt)
        acc[f][nt] = (f32x4){0.f, 0.f, 0.f, 0.f};

    __builtin_amdgcn_s_setprio(1);
    #pragma unroll
    for (int kk = 0; kk < 4; ++kk) {
      #pragma unroll
      for (int nt = 0; nt < 2; ++nt) {
        const int pb = nt * 16 + lm;
        bf16x8 pfr = *reinterpret_cast<const bf16x8*>(
            &Pl[pb * ED + ((kk * 32 + lq * 8) ^ ((pb & 7) << 3))]);
        #pragma unroll
        for (int f = 0; f < 2; ++f)
          acc[f][nt] = __builtin_amdgcn_mfma_f32_16x16x32_bf16(afr[kk][f], pfr, acc[f][nt], 0, 0, 0);
      }
    }
    __builtin_amdgcn_s_setprio(0);

    // ---- partial dot over this warp's e-quarter (NO shuffle/scratch here) ----
    // lane holds T[e = w*32 + f*16 + lq*4 + r][b = nt*16 + lm]
    #pragma unroll
    for (int nt = 0; nt < 2; ++nt) {
      const int qrow = nt * 16 + lm;
      float t0 = 0.f, t1 = 0.f, t2 = 0.f, t3 = 0.f;
      #pragma unroll
      for (int f = 0; f < 2; ++f) {
        const int c = (w * 32 + f * 16 + lq * 4) ^ ((qrow & 7) << 3);
        ushx4 q4 = *reinterpret_cast<const ushx4*>(&Ql[qrow * ED + c]);
        t0 = fmaf(acc[f][nt][0], bf2f(q4[0]), t0);
        t1 = fmaf(acc[f][nt][1], bf2f(q4[1]), t1);
        t2 = fmaf(acc[f][nt][2], bf2f(q4[2]), t2);
        t3 = fmaf(acc[f][nt][3], bf2f(q4[3]), t3);
      }
      res[t][nt] = (t0 + t1) + (t2 + t3);
    }
    __syncthreads();  // reads of cur done; stage(t+1) drained -> safe to proceed
  }

  // ---- deferred epilogue: shuffle + one scratch round-trip for all 8 tiles ----
  #pragma unroll
  for (int t = 0; t < 8; ++t)
    #pragma unroll
    for (int nt = 0; nt < 2; ++nt) {
      float sv = res[t][nt];
      sv += __shfl_xor(sv, 16);   // sum over lq groups (e-sub-quarters)
      sv += __shfl_xor(sv, 32);
      if (lq == 0) scratchF[(w * 8 + t) * 32 + nt * 16 + lm] = sv;
    }
  __syncthreads();
  {
    const int t = tid >> 5;       // 0..7
    const int b = tid & 31;
    const float v = (scratchF[(0 * 8 + t) * 32 + b] + scratchF[(1 * 8 + t) * 32 + b]) +
                    (scratchF[(2 * 8 + t) * 32 + b] + scratchF[(3 * 8 + t) * 32 + b]);
    out[(size_t)(b0base + t * 32 + b) * NIX + n] = v;
  }
}

// ---------------- fallback (proven Round-1 kernel, used when ws too small) ----------------
__device__ __forceinline__ int swz_fb(int row, int col) {
  return row * 128 + (col ^ ((row & 7) << 3));
}

__launch_bounds__(256, 2)
__global__ void opn_fb(const float* __restrict__ x,
                       const float* __restrict__ kern,
                       float* __restrict__ out) {
  __shared__ unsigned short Klds[128 * 128];
  __shared__ unsigned short Plds[64 * 128];
  __shared__ unsigned short Qlds[64 * 132];

  const int n = blockIdx.x;
  const int tid = threadIdx.x;
  const int lane = tid & 63;
  const int w = tid >> 6;
  const int lm = lane & 15;
  const int lq = lane >> 4;

  int fi = 0, base = 0;
  while (base + (NF - 1 - fi) <= n) { base += NF - 1 - fi; ++fi; }
  const int fj = fi + 1 + (n - base);

  {
    const int r8 = tid >> 5;
    const int d0 = (tid & 31) * 4;
    const float* kbp = kern + (size_t)n * ED + d0;
    #pragma unroll
    for (int p = 0; p < 16; ++p) {
      int e = p * 8 + r8;
      float4 v = *reinterpret_cast<const float4*>(kbp + (size_t)e * KROW);
      ushx4 h;
      h[0] = f2bf(v.x); h[1] = f2bf(v.y); h[2] = f2bf(v.z); h[3] = f2bf(v.w);
      *reinterpret_cast<ushx4*>(&Klds[swz_fb(e, d0)]) = h;
    }
  }
  __syncthreads();

  bf16x8 bfr[4][8];
  #pragma unroll
  for (int kk = 0; kk < 4; ++kk)
    #pragma unroll
    for (int f = 0; f < 8; ++f)
      bfr[kk][f] = *reinterpret_cast<const bf16x8*>(
          &Klds[swz_fb(f * 16 + lm, kk * 32 + lq * 8)]);

  const int r8 = tid >> 5;
  const int c4 = (tid & 31) * 4;

  for (int t = 0; t < 8; ++t) {
    const int b0 = blockIdx.y * 512 + t * 64;
    __syncthreads();
    #pragma unroll
    for (int p = 0; p < 8; ++p) {
      int r = p * 8 + r8;
      const float* xbp = x + (size_t)(b0 + r) * XROW + c4;
      float4 vp = *reinterpret_cast<const float4*>(xbp + fi * ED);
      ushx4 hp;
      hp[0] = f2bf(vp.x); hp[1] = f2bf(vp.y); hp[2] = f2bf(vp.z); hp[3] = f2bf(vp.w);
      *reinterpret_cast<ushx4*>(&Plds[swz_fb(r, c4)]) = hp;
      float4 vq = *reinterpret_cast<const float4*>(xbp + fj * ED);
      ushx4 hq;
      hq[0] = f2bf(vq.x); hq[1] = f2bf(vq.y); hq[2] = f2bf(vq.z); hq[3] = f2bf(vq.w);
      *reinterpret_cast<ushx4*>(&Qlds[r * 132 + c4]) = hq;
    }
    __syncthreads();

    f32x4 acc[8];
    #pragma unroll
    for (int f = 0; f < 8; ++f) acc[f] = (f32x4){0.f, 0.f, 0.f, 0.f};
    #pragma unroll
    for (int kk = 0; kk < 4; ++kk) {
      bf16x8 a = *reinterpret_cast<const bf16x8*>(
          &Plds[swz_fb(w * 16 + lm, kk * 32 + lq * 8)]);
      #pragma unroll
      for (int f = 0; f < 8; ++f)
        acc[f] = __builtin_amdgcn_mfma_f32_16x16x32_bf16(a, bfr[kk][f], acc[f], 0, 0, 0);
    }

    #pragma unroll
    for (int r = 0; r < 4; ++r) {
      const int bl = w * 16 + lq * 4 + r;
      float s = 0.f;
      #pragma unroll
      for (int f = 0; f < 8; ++f)
        s = fmaf(acc[f][r], bf2f(Qlds[bl * 132 + f * 16 + lm]), s);
      s += __shfl_xor(s, 1);
      s += __shfl_xor(s, 2);
      s += __shfl_xor(s, 4);
      s += __shfl_xor(s, 8);
      if (lm == 0) out[(size_t)(b0 + bl) * NIX + n] = s;
    }
  }
}

extern "C" void kernel_launch(void* const* d_in, const int* in_sizes, int n_in,
                              void* d_out, int out_size, void* d_ws, size_t ws_size,
                              hipStream_t stream) {
  const float* x = (const float*)d_in[0];
  const float* kern = (const float*)d_in[1];
  float* out = (float*)d_out;
  (void)in_sizes; (void)n_in; (void)out_size;

  if (ws_size >= (size_t)WS_NEED) {
    unsigned short* xb = (unsigned short*)d_ws;
    unsigned short* kbuf = (unsigned short*)((char*)d_ws + XB_BYTES);
    cvt_fused<<<15040, 256, 0, stream>>>(x, kern, xb, kbuf);
    opn_ws<<<3120, 256, 0, stream>>>(xb, kbuf, out);  // 390*8: bid%8 locks b-slice to XCD
  } else {
    dim3 grid(NIX, 2, 1);
    opn_fb<<<grid, 256, 0, stream>>>(x, kern, out);
  }
}

// Round 11
// 103.861 us; speedup vs baseline: 1.2315x; 1.2315x over previous
//
#include <hip/hip_runtime.h>

#define NF 40
#define ED 128
#define NB 1024
#define NIX 780
#define XROW (NF * ED)      // 5120
#define KROW (NIX * ED)     // 99840
#define XB_BYTES (NB * NF * ED * 2)   // 13,107,200
#define KB_BYTES (NIX * ED * ED * 2)  // 25,559,040
#define WS_NEED (XB_BYTES + KB_BYTES)

typedef __attribute__((ext_vector_type(8))) short bf16x8;
typedef __attribute__((ext_vector_type(4))) float f32x4;
typedef __attribute__((ext_vector_type(4))) unsigned short ushx4;
typedef __attribute__((ext_vector_type(8))) unsigned short ushx8;

__device__ __forceinline__ unsigned short f2bf(float x) {
  unsigned int u = __float_as_uint(x);
  u = (u + 0x7FFFu + ((u >> 16) & 1u)) >> 16;
  return (unsigned short)u;
}
__device__ __forceinline__ float bf2f(unsigned short h) {
  return __uint_as_float(((unsigned int)h) << 16);
}
__device__ __forceinline__ int nix_of(int i, int j) {  // triangular pair index
  return i * (2 * NF - i - 1) / 2 + (j - i - 1);
}

#define GLOAD16(gsrc, ldst)                                                    \
  __builtin_amdgcn_global_load_lds(                                            \
      (const __attribute__((address_space(1))) void*)(gsrc),                   \
      (__attribute__((address_space(3))) void*)(ldst), 16, 0, 0)

// ---- fused prepass: x fp32->bf16 (blocks 0..2559), K [e][n][d]->[n][e][d] bf16 ----
__global__ void cvt_fused(const float* __restrict__ x, const float* __restrict__ kr,
                          unsigned short* __restrict__ xb, unsigned short* __restrict__ kb) {
  const int blk = blockIdx.x;
  if (blk < 2560) {
    const size_t g = ((size_t)blk * 256 + threadIdx.x) * 8;
    float4 a = *reinterpret_cast<const float4*>(x + g);
    float4 b = *reinterpret_cast<const float4*>(x + g + 4);
    ushx8 h;
    h[0] = f2bf(a.x); h[1] = f2bf(a.y); h[2] = f2bf(a.z); h[3] = f2bf(a.w);
    h[4] = f2bf(b.x); h[5] = f2bf(b.y); h[6] = f2bf(b.z); h[7] = f2bf(b.w);
    *reinterpret_cast<ushx8*>(xb + g) = h;
  } else {
    const size_t g = ((size_t)(blk - 2560) * 256 + threadIdx.x) * 4;
    const int d = (int)(g & 127);
    const size_t t = g >> 7;
    const int e = (int)(t & 127);
    const int n = (int)(t >> 7);
    float4 v = *reinterpret_cast<const float4*>(kr + ((size_t)e * NIX + n) * ED + d);
    ushx4 h;
    h[0] = f2bf(v.x); h[1] = f2bf(v.y); h[2] = f2bf(v.z); h[3] = f2bf(v.w);
    *reinterpret_cast<ushx4*>(kb + g) = h;
  }
}

// ---- main: 2x2 chunk-pair blocks (4 pairs share 4 planes), 512 thr / 8 warps,
// ---- e-sixteenth per warp (kfr = 64 VGPR), 32-row tiles, 16 waves/CU.
__launch_bounds__(512, 4)
__global__ void opn_ws(const unsigned short* __restrict__ xb,
                       const unsigned short* __restrict__ kb,
                       float* __restrict__ out) {
  // 32 KB region: K staging rounds in prologue; then 4 planes of 8 KB.
  __shared__ unsigned short S[16384];
  __shared__ float scratchF[8 * 4 * 32];   // [warp][pair][b], 4 KB

  const int bid = blockIdx.x;
  const int slice = bid & 3;               // b-slice (adjacent bids share K lines)
  const int wi = bid >> 2;                 // 0..209 work item
  const int b0base = slice * 256;

  const int tid = threadIdx.x;
  const int lane = tid & 63;
  const int w = tid >> 6;                  // 0..7
  const int lm = lane & 15;
  const int lq = lane >> 4;
  const int col8 = lm * 8;

  // ---- decode work item -> field quartet ----
  int fA0, fB0, npairs;
  if (wi < 190) {
    int ca = 0, base = 0;
    while (base + (19 - ca) <= wi) { base += 19 - ca; ++ca; }
    const int cb = ca + 1 + (wi - base);
    fA0 = 2 * ca; fB0 = 2 * cb; npairs = 4;
  } else {
    const int c = wi - 190;
    fA0 = 2 * c; fB0 = 2 * c + 1; npairs = 1;
  }
  // pair p: fi = fA0 + (p>>1), fj = fB0 + (p&1)

  // ---- K staging rounds: stage K_p into S, hoist this warp's e-16th ----
  // afr[kk] covers A[m=e][k=d], e = w*16 + lm, d = kk*32 + lq*8 + j
  bf16x8 kfr0[4], kfr1[4], kfr2[4], kfr3[4];

  auto stageK = [&](int n) {
    const unsigned short* ks = kb + (size_t)n * (ED * ED);
    #pragma unroll
    for (int j = 0; j < 4; ++j) {
      const int chunk = j * 8 + w;         // 0..31, 1 KB each
      const int r = chunk * 4 + lq;        // 0..127
      const int c = col8 ^ ((r & 7) << 3);
      GLOAD16(ks + r * ED + c, S + chunk * 512);
    }
  };
  auto hoistK = [&](bf16x8 (&kf)[4]) {
    const int r = w * 16 + lm;
    #pragma unroll
    for (int kk = 0; kk < 4; ++kk)
      kf[kk] = *reinterpret_cast<const bf16x8*>(
          &S[r * ED + ((kk * 32 + lq * 8) ^ ((r & 7) << 3))]);
    #pragma unroll
    for (int kk = 0; kk < 4; ++kk)
      asm volatile("" : "+v"(kf[kk]));     // pin: forbid remat from LDS
  };

  stageK(nix_of(fA0, fB0));
  __syncthreads();
  hoistK(kfr0);
  __syncthreads();
  if (npairs == 4) {
    stageK(nix_of(fA0, fB0 + 1));
    __syncthreads();
    hoistK(kfr1);
    __syncthreads();
    stageK(nix_of(fA0 + 1, fB0));
    __syncthreads();
    hoistK(kfr2);
    __syncthreads();
    stageK(nix_of(fA0 + 1, fB0 + 1));
    __syncthreads();
    hoistK(kfr3);
    __syncthreads();
  }

  // plane layout (shorts): P0@0, P1@4096, Q0@8192, Q1@12288
  // pair p: P = (p>>1)*4096, Q = 8192 + (p&1)*4096

  // per-pair compute: 8 MFMA + partial dot + scratch write
  auto pair_do = [&](const bf16x8 (&kf)[4], int Poff, int Qoff, int p) {
    f32x4 acc0 = (f32x4){0.f, 0.f, 0.f, 0.f};
    f32x4 acc1 = (f32x4){0.f, 0.f, 0.f, 0.f};
    __builtin_amdgcn_s_setprio(1);
    #pragma unroll
    for (int kk = 0; kk < 4; ++kk) {
      const int cswz = (kk * 32 + lq * 8) ^ ((lm & 7) << 3);
      bf16x8 pf0 = *reinterpret_cast<const bf16x8*>(&S[Poff + lm * ED + cswz]);
      acc0 = __builtin_amdgcn_mfma_f32_16x16x32_bf16(kf[kk], pf0, acc0, 0, 0, 0);
      bf16x8 pf1 = *reinterpret_cast<const bf16x8*>(&S[Poff + (16 + lm) * ED + cswz]);
      acc1 = __builtin_amdgcn_mfma_f32_16x16x32_bf16(kf[kk], pf1, acc1, 0, 0, 0);
    }
    __builtin_amdgcn_s_setprio(0);
    // lane holds T[e = w*16 + lq*4 + r][b = nt*16 + lm]
    const int cq = (w * 16 + lq * 4) ^ ((lm & 7) << 3);
    {
      const int qrow = lm;                 // nt = 0
      ushx4 q4 = *reinterpret_cast<const ushx4*>(&S[Qoff + qrow * ED + cq]);
      float sv = fmaf(acc0[0], bf2f(q4[0]),
                 fmaf(acc0[1], bf2f(q4[1]),
                 fmaf(acc0[2], bf2f(q4[2]), acc0[3] * bf2f(q4[3]))));
      sv += __shfl_xor(sv, 16);
      sv += __shfl_xor(sv, 32);
      if (lq == 0) scratchF[(w * 4 + p) * 32 + qrow] = sv;
    }
    {
      const int qrow = 16 + lm;            // nt = 1
      ushx4 q4 = *reinterpret_cast<const ushx4*>(&S[Qoff + qrow * ED + cq]);
      float sv = fmaf(acc1[0], bf2f(q4[0]),
                 fmaf(acc1[1], bf2f(q4[1]),
                 fmaf(acc1[2], bf2f(q4[2]), acc1[3] * bf2f(q4[3]))));
      sv += __shfl_xor(sv, 16);
      sv += __shfl_xor(sv, 32);
      if (lq == 0) scratchF[(w * 4 + p) * 32 + qrow] = sv;
    }
  };

  #pragma unroll 1
  for (int t = 0; t < 8; ++t) {
    const int b0 = b0base + t * 32;

    // ---- stage planes: 1 gload/thread/plane; row r = w*4+lq, 16 lanes/row ----
    {
      const int r = w * 4 + lq;            // 0..31
      const int c = col8 ^ ((r & 7) << 3);
      const size_t xoff = (size_t)(b0 + r) * XROW + c;
      const int dst = w * 512 + lane * 8;  // linear: wave-uniform base + lane*16B
      GLOAD16(xb + xoff + (size_t)fA0 * ED, S + dst);                    // P0
      GLOAD16(xb + xoff + (size_t)fB0 * ED, S + 8192 + dst);             // Q0
      if (npairs == 4) {
        GLOAD16(xb + xoff + (size_t)(fA0 + 1) * ED, S + 4096 + dst);     // P1
        GLOAD16(xb + xoff + (size_t)(fB0 + 1) * ED, S + 12288 + dst);    // Q1
      }
    }
    __syncthreads();   // tiles staged (barrier drains vmcnt)

    pair_do(kfr0, 0, 8192, 0);
    if (npairs == 4) {
      pair_do(kfr1, 0, 12288, 1);
      pair_do(kfr2, 4096, 8192, 2);
      pair_do(kfr3, 4096, 12288, 3);
    }
    __syncthreads();   // scratch ready; all plane reads done

    // ---- cross-warp reduce + store: 32 b-rows x npairs ----
    if (tid < 32 * npairs) {
      const int p = tid >> 5;              // 0..npairs-1
      const int b = tid & 31;
      float v = 0.f;
      #pragma unroll
      for (int w8 = 0; w8 < 8; ++w8)
        v += scratchF[(w8 * 4 + p) * 32 + b];
      const int fi = fA0 + (p >> 1);
      const int fj = fB0 + (p & 1);
      out[(size_t)(b0 + b) * NIX + nix_of(fi, fj)] = v;
    }
    // next stage overwrites planes only after all compute reads (pre-bar2);
    // next scratch write is separated from this read by the next bar1.
  }
}

// ---------------- fallback (proven Round-1 kernel, used when ws too small) ----------------
__device__ __forceinline__ int swz_fb(int row, int col) {
  return row * 128 + (col ^ ((row & 7) << 3));
}

__launch_bounds__(256, 2)
__global__ void opn_fb(const float* __restrict__ x,
                       const float* __restrict__ kern,
                       float* __restrict__ out) {
  __shared__ unsigned short Klds[128 * 128];
  __shared__ unsigned short Plds[64 * 128];
  __shared__ unsigned short Qlds[64 * 132];

  const int n = blockIdx.x;
  const int tid = threadIdx.x;
  const int lane = tid & 63;
  const int w = tid >> 6;
  const int lm = lane & 15;
  const int lq = lane >> 4;

  int fi = 0, base = 0;
  while (base + (NF - 1 - fi) <= n) { base += NF - 1 - fi; ++fi; }
  const int fj = fi + 1 + (n - base);

  {
    const int r8 = tid >> 5;
    const int d0 = (tid & 31) * 4;
    const float* kbp = kern + (size_t)n * ED + d0;
    #pragma unroll
    for (int p = 0; p < 16; ++p) {
      int e = p * 8 + r8;
      float4 v = *reinterpret_cast<const float4*>(kbp + (size_t)e * KROW);
      ushx4 h;
      h[0] = f2bf(v.x); h[1] = f2bf(v.y); h[2] = f2bf(v.z); h[3] = f2bf(v.w);
      *reinterpret_cast<ushx4*>(&Klds[swz_fb(e, d0)]) = h;
    }
  }
  __syncthreads();

  bf16x8 bfr[4][8];
  #pragma unroll
  for (int kk = 0; kk < 4; ++kk)
    #pragma unroll
    for (int f = 0; f < 8; ++f)
      bfr[kk][f] = *reinterpret_cast<const bf16x8*>(
          &Klds[swz_fb(f * 16 + lm, kk * 32 + lq * 8)]);

  const int r8 = tid >> 5;
  const int c4 = (tid & 31) * 4;

  for (int t = 0; t < 8; ++t) {
    const int b0 = blockIdx.y * 512 + t * 64;
    __syncthreads();
    #pragma unroll
    for (int p = 0; p < 8; ++p) {
      int r = p * 8 + r8;
      const float* xbp = x + (size_t)(b0 + r) * XROW + c4;
      float4 vp = *reinterpret_cast<const float4*>(xbp + fi * ED);
      ushx4 hp;
      hp[0] = f2bf(vp.x); hp[1] = f2bf(vp.y); hp[2] = f2bf(vp.z); hp[3] = f2bf(vp.w);
      *reinterpret_cast<ushx4*>(&Plds[swz_fb(r, c4)]) = hp;
      float4 vq = *reinterpret_cast<const float4*>(xbp + fj * ED);
      ushx4 hq;
      hq[0] = f2bf(vq.x); hq[1] = f2bf(vq.y); hq[2] = f2bf(vq.z); hq[3] = f2bf(vq.w);
      *reinterpret_cast<ushx4*>(&Qlds[r * 132 + c4]) = hq;
    }
    __syncthreads();

    f32x4 acc[8];
    #pragma unroll
    for (int f = 0; f < 8; ++f) acc[f] = (f32x4){0.f, 0.f, 0.f, 0.f};
    #pragma unroll
    for (int kk = 0; kk < 4; ++kk) {
      bf16x8 a = *reinterpret_cast<const bf16x8*>(
          &Plds[swz_fb(w * 16 + lm, kk * 32 + lq * 8)]);
      #pragma unroll
      for (int f = 0; f < 8; ++f)
        acc[f] = __builtin_amdgcn_mfma_f32_16x16x32_bf16(a, bfr[kk][f], acc[f], 0, 0, 0);
    }

    #pragma unroll
    for (int r = 0; r < 4; ++r) {
      const int bl = w * 16 + lq * 4 + r;
      float s = 0.f;
      #pragma unroll
      for (int f = 0; f < 8; ++f)
        s = fmaf(acc[f][r], bf2f(Qlds[bl * 132 + f * 16 + lm]), s);
      s += __shfl_xor(s, 1);
      s += __shfl_xor(s, 2);
      s += __shfl_xor(s, 4);
      s += __shfl_xor(s, 8);
      if (lm == 0) out[(size_t)(b0 + bl) * NIX + n] = s;
    }
  }
}

extern "C" void kernel_launch(void* const* d_in, const int* in_sizes, int n_in,
                              void* d_out, int out_size, void* d_ws, size_t ws_size,
                              hipStream_t stream) {
  const float* x = (const float*)d_in[0];
  const float* kern = (const float*)d_in[1];
  float* out = (float*)d_out;
  (void)in_sizes; (void)n_in; (void)out_size;

  if (ws_size >= (size_t)WS_NEED) {
    unsigned short* xb = (unsigned short*)d_ws;
    unsigned short* kbuf = (unsigned short*)((char*)d_ws + XB_BYTES);
    cvt_fused<<<15040, 256, 0, stream>>>(x, kern, xb, kbuf);
    // 210 work items (190 cross 2x2 chunk-pairs + 20 diag) x 4 b-slices
    opn_ws<<<840, 512, 0, stream>>>(xb, kbuf, out);
  } else {
    dim3 grid(NIX, 2, 1);
    opn_fb<<<grid, 256, 0, stream>>>(x, kern, out);
  }
}